// Round 12
// baseline (1286.054 us; speedup 1.0000x reference)
//
#include <hip/hip_runtime.h>
#include <hip/hip_bf16.h>

typedef __hip_bfloat16 bf16;
typedef __hip_bfloat162 bf162;

#define U_N   100000
#define B_N   50000
#define N_TOT 150000
#define NE_UB 800000
#define NE_BB 600000
#define NP    400000
#define DU    64
#define DB    128
#define HD    128

__device__ __forceinline__ float b2f(bf16 v) { return __bfloat162float(v); }
__device__ __forceinline__ float2 ldb2(const bf16* row, int lane) {
    bf162 v = ((const bf162*)row)[lane];
    return make_float2(b2f(v.x), b2f(v.y));
}
__device__ __forceinline__ void stb2(bf16* row, int lane, float2 v) {
    bf162 o;
    o.x = __float2bfloat16(v.x);
    o.y = __float2bfloat16(v.y);
    ((bf162*)row)[lane] = o;
}
__device__ __forceinline__ float bflo(unsigned v) { return __uint_as_float(v << 16); }
__device__ __forceinline__ float bfhi(unsigned v) { return __uint_as_float(v & 0xffff0000u); }

// ---------------- merged init GEMMs (3 independent GEMMs, one launch) ----------------

template<int K>
__device__ __forceinline__
void gemm16_dev(const float* __restrict__ x, const float* __restrict__ W,
                const float* __restrict__ bias, bf16* out16, int nrows,
                int blk, float* srow) {
    const int c  = threadIdx.x;
    const int r0 = blk * 16;
    for (int i = threadIdx.x; i < 16 * K; i += 128) {
        int rr = i / K, kk = i % K;
        int r = r0 + rr;
        srow[rr * K + kk] = (r < nrows) ? x[(size_t)r * K + kk] : 0.0f;
    }
    __syncthreads();
    float acc[16];
#pragma unroll
    for (int i = 0; i < 16; i++) acc[i] = 0.0f;
    for (int k = 0; k < K; k++) {
        float w = W[k * HD + c];
#pragma unroll
        for (int i = 0; i < 16; i++) acc[i] = fmaf(srow[i * K + k], w, acc[i]);
    }
    float bv = bias[c];
#pragma unroll
    for (int i = 0; i < 16; i++) {
        int r = r0 + i;
        if (r < nrows) out16[(size_t)r * HD + c] = __float2bfloat16(acc[i] + bv);
    }
}

__global__ __launch_bounds__(128)
void k_init_all(const float* __restrict__ user_x, const float* __restrict__ Wu,
                const float* __restrict__ bu,
                const float* __restrict__ book_x, const float* __restrict__ Wub,
                const float* __restrict__ bub,
                const float* __restrict__ Wbb, const float* __restrict__ bbb,
                bf16* X016, bf16* h16) {
    __shared__ float srow[16 * DB];
    const int NBU = (U_N + 15) / 16;   // 6250
    const int NBB = (B_N + 15) / 16;   // 3125
    int b = blockIdx.x;
    if (b < NBU) {
        gemm16_dev<DU>(user_x, Wu, bu, X016, U_N, b, srow);
    } else if (b < NBU + NBB) {
        gemm16_dev<DB>(book_x, Wub, bub, X016 + (size_t)U_N * HD, B_N, b - NBU, srow);
    } else {
        gemm16_dev<DB>(book_x, Wbb, bbb, h16, B_N, b - NBU - NBB, srow);
    }
}

// ---------------- CSR build: merged count -> merged scan -> merged fill ----------------

__global__ void k_cnt_all(const int* __restrict__ us, const int* __restrict__ ud,
                          const int* __restrict__ bd,
                          int* __restrict__ cnt_ub, int* __restrict__ cnt_bb) {
    int e = blockIdx.x * blockDim.x + threadIdx.x;
    if (e < NE_UB) {
        atomicAdd(&cnt_ub[us[e]], 1);
        atomicAdd(&cnt_ub[U_N + ud[e]], 1);
    }
    if (e < NE_BB) atomicAdd(&cnt_bb[bd[e]], 1);
}

__global__ void k_dinv(const int* __restrict__ cnt, float* __restrict__ dinv) {
    int i = blockIdx.x * blockDim.x + threadIdx.x;
    if (i < N_TOT) {
        int d = cnt[i];
        dinv[i] = (d > 0) ? 1.0f / sqrtf((float)d) : 0.0f;
    }
}

__device__ __forceinline__
void scan1_dev(const int* __restrict__ cnt, int* __restrict__ rs,
               int* __restrict__ bsum, int n, int blk, int* ts) {
    const int t = threadIdx.x;
    const int base = blk * 1024 + t * 4;
    int v0 = (base + 0 < n) ? cnt[base + 0] : 0;
    int v1 = (base + 1 < n) ? cnt[base + 1] : 0;
    int v2 = (base + 2 < n) ? cnt[base + 2] : 0;
    int v3 = (base + 3 < n) ? cnt[base + 3] : 0;
    int local = v0 + v1 + v2 + v3;
    ts[t] = local;
    __syncthreads();
    for (int off = 1; off < 256; off <<= 1) {
        int x = (t >= off) ? ts[t - off] : 0;
        __syncthreads();
        ts[t] += x;
        __syncthreads();
    }
    int ex = ts[t] - local;
    if (base + 0 < n) rs[base + 0] = ex;
    if (base + 1 < n) rs[base + 1] = ex + v0;
    if (base + 2 < n) rs[base + 2] = ex + v0 + v1;
    if (base + 3 < n) rs[base + 3] = ex + v0 + v1 + v2;
    if (t == 0) bsum[blk] = ts[255];
}

#define NB_SC_UB ((N_TOT + 1023) / 1024)   // 147
#define NB_SC_BB ((B_N + 1023) / 1024)     // 49

__global__ void k_scan1_all(const int* __restrict__ cnt_ub, int* __restrict__ rs_ub,
                            int* __restrict__ bsum_ub,
                            const int* __restrict__ cnt_bb, int* __restrict__ rs_bb,
                            int* __restrict__ bsum_bb) {
    __shared__ int ts[256];
    int b = blockIdx.x;
    if (b < NB_SC_UB) scan1_dev(cnt_ub, rs_ub, bsum_ub, N_TOT, b, ts);
    else              scan1_dev(cnt_bb, rs_bb, bsum_bb, B_N, b - NB_SC_UB, ts);
}

__device__ __forceinline__
void scan2_dev(int* __restrict__ bsum, int nb, int* ts) {
    const int t = threadIdx.x;
    const int base = t * 4;
    int v0 = (base + 0 < nb) ? bsum[base + 0] : 0;
    int v1 = (base + 1 < nb) ? bsum[base + 1] : 0;
    int v2 = (base + 2 < nb) ? bsum[base + 2] : 0;
    int v3 = (base + 3 < nb) ? bsum[base + 3] : 0;
    int local = v0 + v1 + v2 + v3;
    ts[t] = local;
    __syncthreads();
    for (int off = 1; off < 256; off <<= 1) {
        int x = (t >= off) ? ts[t - off] : 0;
        __syncthreads();
        ts[t] += x;
        __syncthreads();
    }
    int ex = ts[t] - local;
    if (base + 0 < nb) bsum[base + 0] = ex;
    if (base + 1 < nb) bsum[base + 1] = ex + v0;
    if (base + 2 < nb) bsum[base + 2] = ex + v0 + v1;
    if (base + 3 < nb) bsum[base + 3] = ex + v0 + v1 + v2;
}

__global__ void k_scan2_all(int* __restrict__ bsum_ub, int* __restrict__ bsum_bb) {
    __shared__ int ts[256];
    if (blockIdx.x == 0) scan2_dev(bsum_ub, NB_SC_UB, ts);
    else                 scan2_dev(bsum_bb, NB_SC_BB, ts);
}

#define NB3_UB ((N_TOT + 255) / 256)   // 587
#define NB3_BB ((B_N + 255) / 256)     // 196

__global__ void k_scan3_all(int* __restrict__ rs_ub, const int* __restrict__ bsum_ub,
                            int* __restrict__ rs_bb, const int* __restrict__ bsum_bb) {
    int b = blockIdx.x;
    if (b < NB3_UB) {
        int i = b * 256 + threadIdx.x;
        if (i < N_TOT) rs_ub[i] += bsum_ub[i >> 10];
    } else {
        int i = (b - NB3_UB) * 256 + threadIdx.x;
        if (i < B_N) rs_bb[i] += bsum_bb[i >> 10];
    }
}

// fill both CSRs in one launch; rs arrays become end-offsets
__global__ void k_fill_all(const int* __restrict__ us, const int* __restrict__ ud,
                           int* __restrict__ rs_ub, int* __restrict__ eidx_ub,
                           const int* __restrict__ bs, const int* __restrict__ bd,
                           int* __restrict__ rs_bb, int* __restrict__ eidx_bb) {
    int e = blockIdx.x * blockDim.x + threadIdx.x;
    if (e < NE_UB) {
        int u = us[e];
        int b = U_N + ud[e];
        int pu = atomicAdd(&rs_ub[u], 1);
        eidx_ub[pu] = b;
        int pb = atomicAdd(&rs_ub[b], 1);
        eidx_ub[pb] = u;
    }
    if (e < NE_BB) {
        int p = atomicAdd(&rs_bb[bd[e]], 1);
        eidx_bb[p] = bs[e];
    }
}

// ---------------- pull-mode propagation (bf16 tables, f32 accumulate) ----------------

__global__ void k_gather1(const int* __restrict__ rs, const int* __restrict__ eidx,
                          const float* __restrict__ dinv,
                          const bf16* __restrict__ x016, bf16* __restrict__ x116) {
    int w    = (blockIdx.x * blockDim.x + threadIdx.x) >> 6;
    int lane = threadIdx.x & 63;
    if (w >= N_TOT) return;
    int s = (w == 0) ? 0 : rs[w - 1];
    int e = rs[w];
    s = __builtin_amdgcn_readfirstlane(s);
    e = __builtin_amdgcn_readfirstlane(e);
    float nd = dinv[w];
    float2 acc = make_float2(0.0f, 0.0f);
    for (int j = s; j < e; ++j) {
        int nb = eidx[j];
        float wgt = nd * dinv[nb];
        float2 v = ldb2(x016 + (size_t)nb * HD, lane);
        acc.x = fmaf(v.x, wgt, acc.x);
        acc.y = fmaf(v.y, wgt, acc.y);
    }
    stb2(x116 + (size_t)w * HD, lane, acc);
}

__global__ void k_gather2(const int* __restrict__ rs, const int* __restrict__ eidx,
                          const float* __restrict__ dinv,
                          const bf16* __restrict__ x016, const bf16* __restrict__ x116,
                          bf16* __restrict__ xf16) {
    int w    = (blockIdx.x * blockDim.x + threadIdx.x) >> 6;
    int lane = threadIdx.x & 63;
    if (w >= N_TOT) return;
    int s = (w == 0) ? 0 : rs[w - 1];
    int e = rs[w];
    s = __builtin_amdgcn_readfirstlane(s);
    e = __builtin_amdgcn_readfirstlane(e);
    float nd = dinv[w];
    float2 acc = make_float2(0.0f, 0.0f);
    for (int j = s; j < e; ++j) {
        int nb = eidx[j];
        float wgt = nd * dinv[nb];
        float2 v = ldb2(x116 + (size_t)nb * HD, lane);
        acc.x = fmaf(v.x, wgt, acc.x);
        acc.y = fmaf(v.y, wgt, acc.y);
    }
    float2 a = ldb2(x016 + (size_t)w * HD, lane);
    float2 b = ldb2(x116 + (size_t)w * HD, lane);
    acc.x = (acc.x + a.x + b.x) * (1.0f / 3.0f);
    acc.y = (acc.y + a.y + b.y) * (1.0f / 3.0f);
    stb2(xf16 + (size_t)w * HD, lane, acc);
}

// ---------------- fused mean-aggregate + GEMM layer ----------------
// out16[r] = relu( (mean_nb hnb[nb]) @ Wl + bl + hnb[r] @ Wr )
// OUT BUFFER MUST NOT ALIAS hnb: other blocks read hnb rows as neighbors.
__global__ __launch_bounds__(128)
void k_glayerF(const int* __restrict__ rs, const int* __restrict__ eidx,
               const bf16* __restrict__ hnb,
               const float* __restrict__ Wl, const float* __restrict__ bl,
               const float* __restrict__ Wr, bf16* __restrict__ out16) {
    __shared__ float sa[16][HD];
    __shared__ float sh[16][HD];
    const int c  = threadIdx.x;
    const int r0 = blockIdx.x * 16;
    for (int i = 0; i < 16; i++) {
        int r = r0 + i;
        float acc = 0.0f;
        int deg = 0;
        if (r < B_N) {
            int s = (r == 0) ? 0 : rs[r - 1];
            int e = rs[r];
            deg = e - s;
            for (int j = s; j < e; ++j) {
                int nb = eidx[j];
                acc += b2f(hnb[(size_t)nb * HD + c]);
            }
            sh[i][c] = b2f(hnb[(size_t)r * HD + c]);
        } else {
            sh[i][c] = 0.0f;
        }
        sa[i][c] = acc / fmaxf((float)deg, 1.0f);
    }
    __syncthreads();
    float acc[16];
#pragma unroll
    for (int i = 0; i < 16; i++) acc[i] = 0.0f;
    for (int k = 0; k < HD; k++) {
        float wl = Wl[k * HD + c];
        float wr = Wr[k * HD + c];
#pragma unroll
        for (int i = 0; i < 16; i++) {
            acc[i] = fmaf(sa[i][k], wl, acc[i]);
            acc[i] = fmaf(sh[i][k], wr, acc[i]);
        }
    }
    float bv = bl[c];
#pragma unroll
    for (int i = 0; i < 16; i++) {
        int r = r0 + i;
        if (r < B_N)
            out16[(size_t)r * HD + c] = __float2bfloat16(fmaxf(acc[i] + bv, 0.0f));
    }
}

// attention fusion head, 8 rows per 128-thread block (2 waves); bf16 in/out
__global__ __launch_bounds__(128)
void k_fuse(const bf16* __restrict__ collab16, const bf16* __restrict__ content16,
            const float* __restrict__ Wf1, const float* __restrict__ bf1v,
            const float* __restrict__ Wf2, const float* __restrict__ bf2v,
            bf16* __restrict__ fused16) {
    const int R = 8;
    __shared__ float sc[R][HD];
    __shared__ float sh[R][HD];
    __shared__ float part[2][R][2];
    __shared__ float attn[R][2];
    const int c  = threadIdx.x;
    const int r0 = blockIdx.x * R;
#pragma unroll
    for (int i = 0; i < R; i++) {
        int r = r0 + i;
        sc[i][c] = (r < B_N) ? b2f(collab16[(size_t)r * HD + c]) : 0.0f;
        sh[i][c] = (r < B_N) ? b2f(content16[(size_t)r * HD + c]) : 0.0f;
    }
    __syncthreads();
    float t[R];
#pragma unroll
    for (int i = 0; i < R; i++) t[i] = 0.0f;
    for (int k = 0; k < HD; k++) {
        float w = Wf1[k * HD + c];
#pragma unroll
        for (int i = 0; i < R; i++) t[i] = fmaf(sc[i][k], w, t[i]);
    }
    for (int k = 0; k < HD; k++) {
        float w = Wf1[(size_t)(HD + k) * HD + c];
#pragma unroll
        for (int i = 0; i < R; i++) t[i] = fmaf(sh[i][k], w, t[i]);
    }
    float b1  = bf1v[c];
    float w20 = Wf2[c * 2 + 0];
    float w21 = Wf2[c * 2 + 1];
    float p0[R], p1[R];
#pragma unroll
    for (int i = 0; i < R; i++) {
        float tv = fmaxf(t[i] + b1, 0.0f);
        p0[i] = tv * w20;
        p1[i] = tv * w21;
    }
#pragma unroll
    for (int i = 0; i < R; i++) {
        for (int off = 32; off > 0; off >>= 1) {
            p0[i] += __shfl_down(p0[i], off, 64);
            p1[i] += __shfl_down(p1[i], off, 64);
        }
    }
    int wv   = threadIdx.x >> 6;
    int lane = threadIdx.x & 63;
    if (lane == 0) {
#pragma unroll
        for (int i = 0; i < R; i++) { part[wv][i][0] = p0[i]; part[wv][i][1] = p1[i]; }
    }
    __syncthreads();
    if (threadIdx.x < R) {
        int i = threadIdx.x;
        float s0 = part[0][i][0] + part[1][i][0] + bf2v[0];
        float s1 = part[0][i][1] + part[1][i][1] + bf2v[1];
        float m  = fmaxf(s0, s1);
        float e0 = expf(s0 - m), e1 = expf(s1 - m);
        float inv = 1.0f / (e0 + e1);
        attn[i][0] = e0 * inv;
        attn[i][1] = e1 * inv;
    }
    __syncthreads();
#pragma unroll
    for (int i = 0; i < R; i++) {
        int r = r0 + i;
        if (r < B_N) {
            float v = attn[i][0] * sc[i][c] + attn[i][1] * sh[i][c];
            fused16[(size_t)r * HD + c] = __float2bfloat16(v);
        }
    }
}

// half-wave (32 lanes) per prediction; each lane reads 8B of each 256B row
__global__ void k_score(const int* __restrict__ pu, const int* __restrict__ pb,
                        const bf16* __restrict__ uemb16, const bf16* __restrict__ fused16,
                        float* __restrict__ out) {
    int pid  = (blockIdx.x * blockDim.x + threadIdx.x) >> 5;
    int lane = threadIdx.x & 31;
    if (pid >= NP) return;
    int u = pu[pid];
    int b = pb[pid];
    uint2 a = ((const uint2*)(uemb16 + (size_t)u * HD))[lane];
    uint2 f = ((const uint2*)(fused16 + (size_t)b * HD))[lane];
    float s = bflo(a.x) * bflo(f.x) + bfhi(a.x) * bfhi(f.x)
            + bflo(a.y) * bflo(f.y) + bfhi(a.y) * bfhi(f.y);
    for (int off = 16; off > 0; off >>= 1) s += __shfl_down(s, off, 32);
    if (lane == 0) out[pid] = s;
}

extern "C" void kernel_launch(void* const* d_in, const int* in_sizes, int n_in,
                              void* d_out, int out_size, void* d_ws, size_t ws_size,
                              hipStream_t stream) {
    const float* user_x = (const float*)d_in[0];
    const float* book_x = (const float*)d_in[1];
    const int*   ub_src = (const int*)d_in[2];
    const int*   ub_dst = (const int*)d_in[3];
    const int*   bb_src = (const int*)d_in[4];
    const int*   bb_dst = (const int*)d_in[5];
    const int*   pred_u = (const int*)d_in[6];
    const int*   pred_b = (const int*)d_in[7];
    const float* Wu   = (const float*)d_in[8];
    const float* bu   = (const float*)d_in[9];
    const float* Wub  = (const float*)d_in[10];
    const float* bub  = (const float*)d_in[11];
    const float* Wbb  = (const float*)d_in[12];
    const float* bbb  = (const float*)d_in[13];
    const float* Wl1  = (const float*)d_in[14];
    const float* bl1  = (const float*)d_in[15];
    const float* Wr1  = (const float*)d_in[16];
    const float* Wl2  = (const float*)d_in[17];
    const float* bl2  = (const float*)d_in[18];
    const float* Wr2  = (const float*)d_in[19];
    const float* Wf1  = (const float*)d_in[20];
    const float* bf1v = (const float*)d_in[21];
    const float* Wf2  = (const float*)d_in[22];
    const float* bf2v = (const float*)d_in[23];
    float* out = (float*)d_out;

    // ---- workspace layout (words): 37.96M = 151.84 MB (proven >=162.24 avail) ----
    // 0..150000        dinv
    // 150000..300000   cnt_ub
    // 300000..450000   rs_ub
    // 450000..500000   cnt_bb
    // 500000..550000   rs_bb
    // 550000..560000   bsum_ub(147)@550000 | bsum_bb(49)@551024
    // 560000..2160000  eidx_ub (1.6M)
    // 2160000..2760000 eidx_bb (600k)
    // 2760000..5960000 h16  (B*H bf16)   -> content16 after layer2
    // 5960000..9160000 h2_16 (B*H bf16)  -> fused16 after fuse
    // 9160000..18760000   X016 bf16 N*H
    // 18760000..28360000  X1_16 bf16 N*H
    // 28360000..37960000  XF16 bf16 N*H (uemb rows 0..U, collab rows U..N)
    float* ws = (float*)d_ws;
    const size_t need = 37960000ull * sizeof(float);
    if (ws_size < need) return;

    float* dinv    = ws;
    int*   cnt_ub  = (int*)(ws + 150000);
    int*   rs_ub   = (int*)(ws + 300000);
    int*   cnt_bb  = (int*)(ws + 450000);
    int*   rs_bb   = (int*)(ws + 500000);
    int*   bsum_ub = (int*)(ws + 550000);
    int*   bsum_bb = (int*)(ws + 551024);
    int*   eidx_ub = (int*)(ws + 560000);
    int*   eidx_bb = (int*)(ws + 2160000);
    bf16*  h16     = (bf16*)(ws + 2760000);
    bf16*  h2_16   = (bf16*)(ws + 5960000);
    bf16*  X016    = (bf16*)(ws + 9160000);
    bf16*  X1_16   = (bf16*)(ws + 18760000);
    bf16*  XF16    = (bf16*)(ws + 28360000);
    bf16*  content16 = h16;                     // layer2 out over h16 (dead, no race)
    bf16*  fused16   = h2_16;                   // fuse out over h2_16 (dead, no race)
    bf16*  uemb16    = XF16;
    bf16*  collab16  = XF16 + (size_t)U_N * HD;

    // zero cnt_ub..cnt_bb (rs/bsum fully overwritten by scans)
    hipMemsetAsync(ws + 150000, 0, 350000 * sizeof(float), stream);

    // all three input GEMMs in one launch (independent)
    k_init_all<<<(U_N + 15) / 16 + 2 * ((B_N + 15) / 16), 128, 0, stream>>>(
        user_x, Wu, bu, book_x, Wub, bub, Wbb, bbb, X016, h16);

    // merged CSR builds
    k_cnt_all<<<(NE_UB + 255) / 256, 256, 0, stream>>>(ub_src, ub_dst, bb_dst,
                                                       cnt_ub, cnt_bb);
    k_dinv<<<(N_TOT + 255) / 256, 256, 0, stream>>>(cnt_ub, dinv);
    k_scan1_all<<<NB_SC_UB + NB_SC_BB, 256, 0, stream>>>(cnt_ub, rs_ub, bsum_ub,
                                                         cnt_bb, rs_bb, bsum_bb);
    k_scan2_all<<<2, 256, 0, stream>>>(bsum_ub, bsum_bb);
    k_scan3_all<<<NB3_UB + NB3_BB, 256, 0, stream>>>(rs_ub, bsum_ub, rs_bb, bsum_bb);
    k_fill_all<<<(NE_UB + 255) / 256, 256, 0, stream>>>(ub_src, ub_dst, rs_ub, eidx_ub,
                                                        bb_src, bb_dst, rs_bb, eidx_bb);

    // LightGCN propagation
    k_gather1<<<(N_TOT + 3) / 4, 256, 0, stream>>>(rs_ub, eidx_ub, dinv, X016, X1_16);
    k_gather2<<<(N_TOT + 3) / 4, 256, 0, stream>>>(rs_ub, eidx_ub, dinv,
                                                   X016, X1_16, XF16);

    // content network: fused mean-aggregate + GEMM, ping-pong buffers
    k_glayerF<<<(B_N + 15) / 16, 128, 0, stream>>>(rs_bb, eidx_bb, h16,
                                                   Wl1, bl1, Wr1, h2_16);
    k_glayerF<<<(B_N + 15) / 16, 128, 0, stream>>>(rs_bb, eidx_bb, h2_16,
                                                   Wl2, bl2, Wr2, content16);

    // fusion + scores
    k_fuse<<<(B_N + 7) / 8, 128, 0, stream>>>(collab16, content16,
                                              Wf1, bf1v, Wf2, bf2v, fused16);
    k_score<<<(NP + 7) / 8, 256, 0, stream>>>(pred_u, pred_b, uemb16, fused16, out);
}